// Round 3
// baseline (7547.131 us; speedup 1.0000x reference)
//
#include <hip/hip_runtime.h>

#define SEQ   1024
#define HID   512
#define OUTD  10
#define RPB   16              // rows per row-group
#define NRG   32              // row-groups (32*16 = 512 batch)
#define NCG   4               // column-groups (blocks per row-group)
#define CPB   (HID / NCG)     // 128 cols per block
#define NWV   4               // waves per block
#define CPWV  (CPB / NWV)     // 32 cols per wave
#define NT    (CPWV / 16)     // 2 MFMA col-tiles per wave
#define NKT   (HID / 32)      // 16 K-tiles of 32

typedef float  f32x4  __attribute__((ext_vector_type(4)));
typedef float  f32x4v __attribute__((ext_vector_type(4)));
typedef short  bf16x8 __attribute__((ext_vector_type(8)));
typedef int    i32x4  __attribute__((ext_vector_type(4)));

__device__ __forceinline__ unsigned short f2bf(float f) {
    unsigned u = __builtin_bit_cast(unsigned, f);
    u += 0x7fffu + ((u >> 16) & 1u);           // RTN
    return (unsigned short)(u >> 16);
}
__device__ __forceinline__ float bf2f(unsigned short s) {
    return __builtin_bit_cast(float, ((unsigned)s) << 16);
}

// zero the exchange flags (d_ws is re-poisoned 0xAA before every launch)
__global__ void ws_init(unsigned* __restrict__ flags) {
    if (threadIdx.x < NRG * NCG) flags[threadIdx.x] = 0u;
}

// Persistent column-split RNN. Block bid = cg*32 + rg owns rows [16rg,16rg+16)
// x cols [128cg, 128cg+128). W-slice lives in VGPRs (128/thread). Per step the
// 4 col-group blocks of a row-group exchange h slices through global hX[2]
// (double-buffered) with monotonic agent-scope flags.
// MFMA 16x16x32 bf16 (empirically verified in round 2):
//   A lane l -> row=l&15, k=(l>>4)*8+j ; B lane l -> col=l&15, same k
//   D lane l -> col=l&15, row=(l>>4)*4+r
__global__ __launch_bounds__(256, 1) void rnn_kernel(
    const float* __restrict__ x,     // [512][1024]
    const float* __restrict__ W_hx,  // [512][1]
    const float* __restrict__ b_hx,  // [512]
    const float* __restrict__ W_hh,  // [512][512]
    const float* __restrict__ b_hh,  // [512]
    const float* __restrict__ W_oh,  // [10][512]
    const float* __restrict__ b_oh,  // [10]
    float* __restrict__ out,         // [512][10]
    unsigned short* __restrict__ hX, // [2][512][512] bf16 exchange buffer (ws)
    unsigned* __restrict__ flags)    // [4][32] monotonic step counters (ws)
{
    __shared__ unsigned short hL[RPB * HID];   // 16 KB, swizzle-stored h_t rows
    __shared__ float obuf[RPB][OUTD];

    const int bid  = blockIdx.x;
    const int rg   = bid & 31;        // same-XCD grouping under round-robin
    const int cg   = bid >> 5;
    const int row0 = rg * RPB;
    const int col0 = cg * CPB;
    const int tid  = threadIdx.x;
    const int lane = tid & 63;
    const int wv   = tid >> 6;
    const int crow = lane & 15;       // A-row / B-col / D-col
    const int kb   = lane >> 4;       // k quarter
    const int dr0  = kb * 4;          // D row base

    // ---- W-slice -> registers (fp32 -> bf16 once; one-time, ~256 KB/block) ----
    bf16x8 wfr[NT][NKT];
    float  whx[NT], bc[NT];
#pragma unroll
    for (int nt = 0; nt < NT; ++nt) {
        const int col = col0 + wv * CPWV + nt * 16 + crow;
        whx[nt] = W_hx[col];
        bc[nt]  = b_hx[col] + b_hh[col];
#pragma unroll
        for (int kt = 0; kt < NKT; ++kt) {
            const float* p = W_hh + (size_t)col * HID + kt * 32 + kb * 8;
            bf16x8 v;
#pragma unroll
            for (int j = 0; j < 8; ++j) v[j] = (short)f2bf(p[j]);
            wfr[nt][kt] = v;
        }
    }

    // sibling flag index for poller threads 0..2 (skip own cg)
    unsigned sidx = 0;
    if (tid < 3) {
        int cgs = tid + (tid >= cg ? 1 : 0);
        sidx = (unsigned)(cgs * NRG + rg);
    }

    for (int t = 0; t < SEQ; ++t) {
        // x values for this lane's 4 D-rows (consumed in epilogue)
        float xv[4];
#pragma unroll
        for (int r = 0; r < 4; ++r)
            xv[r] = x[(size_t)(row0 + dr0 + r) * SEQ + t];

        f32x4 acc[NT];
#pragma unroll
        for (int nt = 0; nt < NT; ++nt) acc[nt] = (f32x4){0.f, 0.f, 0.f, 0.f};

        if (t > 0) {
            // ---- wait for siblings' h_t slices ----
            if (tid < 3) {
                while (__hip_atomic_load(&flags[sidx], __ATOMIC_ACQUIRE,
                                         __HIP_MEMORY_SCOPE_AGENT) < (unsigned)t)
                    __builtin_amdgcn_s_sleep(1);
            }
            __syncthreads();  // B1: poll done; prev-step LDS reads all retired

            // ---- stage h_t rows (16 KB) global -> LDS, source-XOR-swizzled ----
            const char* hsrc = (const char*)hX + (size_t)(t & 1) * HID * HID * 2;
            i32x4 tmp[4];
#pragma unroll
            for (int p = 0; p < 4; ++p) {
                int c   = p * 256 + tid;          // 16B chunk id, 0..1023
                int row = c >> 6;                 // local row 0..15
                int off = ((c & 63) * 16) ^ ((row & 7) << 4);
                tmp[p] = *(const i32x4*)(hsrc + (size_t)(row0 + row) * 1024 + off);
            }
#pragma unroll
            for (int p = 0; p < 4; ++p) {
                int c = p * 256 + tid;
                *(i32x4*)((char*)hL + c * 16) = tmp[p];
            }
            __syncthreads();  // B2: hL ready

            // ---- GEMM: load all 16 A-fragments, then 32 MFMAs ----
            bf16x8 a[NKT];
#pragma unroll
            for (int kt = 0; kt < NKT; ++kt) {
                int ad = (crow * 1024 + kt * 64 + kb * 16) ^ ((crow & 7) << 4);
                a[kt] = *(const bf16x8*)((const char*)hL + ad);
            }
#pragma unroll
            for (int kt = 0; kt < NKT; ++kt)
#pragma unroll
                for (int nt = 0; nt < NT; ++nt)
                    acc[nt] = __builtin_amdgcn_mfma_f32_16x16x32_bf16(
                        a[kt], wfr[nt][kt], acc[nt], 0, 0, 0);
        }

        // ---- epilogue: pre-activation, tanh, publish h_{t+1} slice ----
        unsigned short* hdst = hX + (size_t)((t + 1) & 1) * HID * HID;
#pragma unroll
        for (int nt = 0; nt < NT; ++nt) {
#pragma unroll
            for (int r = 0; r < 4; ++r) {
                float pre = acc[nt][r] + xv[r] * whx[nt] + bc[nt];
                float e   = __expf(2.0f * pre);       // overflow -> inf -> h=1
                float h   = 1.0f - 2.0f / (e + 1.0f);
                int row = dr0 + r;
                int col = col0 + wv * CPWV + nt * 16 + crow;
                hdst[(size_t)(row0 + row) * HID + col] = f2bf(h);
            }
        }
        __syncthreads();  // B3: all stores drained to L2 (vmcnt(0) before barrier)
        if (tid == 0)
            __hip_atomic_store(&flags[bid], (unsigned)(t + 1), __ATOMIC_RELEASE,
                               __HIP_MEMORY_SCOPE_AGENT);
    }

    // ---- output projection + softmax (cg==0 blocks only) ----
    if (cg != 0) return;
    if (tid < 3) {
        while (__hip_atomic_load(&flags[sidx], __ATOMIC_ACQUIRE,
                                 __HIP_MEMORY_SCOPE_AGENT) < (unsigned)SEQ)
            __builtin_amdgcn_s_sleep(1);
    }
    __syncthreads();

    const unsigned short* hf = hX;   // h_{1024} lives in buffer (SEQ & 1) == 0
    if (tid < RPB * OUTD) {
        int bl = tid / OUTD, j = tid % OUTD;
        const unsigned short* hrow = hf + (size_t)(row0 + bl) * HID;
        const float* wrow = W_oh + (size_t)j * HID;
        float s = b_oh[j];
        for (int k = 0; k < HID; ++k) s += bf2f(hrow[k]) * wrow[k];
        obuf[bl][j] = s;
    }
    __syncthreads();
    if (tid < RPB) {
        float m = -1e30f;
#pragma unroll
        for (int j = 0; j < OUTD; ++j) m = fmaxf(m, obuf[tid][j]);
        float e[OUTD], ss = 0.f;
#pragma unroll
        for (int j = 0; j < OUTD; ++j) { e[j] = __expf(obuf[tid][j] - m); ss += e[j]; }
        float inv = 1.0f / ss;
#pragma unroll
        for (int j = 0; j < OUTD; ++j)
            out[(size_t)(row0 + tid) * OUTD + j] = e[j] * inv;
    }
}

extern "C" void kernel_launch(void* const* d_in, const int* in_sizes, int n_in,
                              void* d_out, int out_size, void* d_ws, size_t ws_size,
                              hipStream_t stream) {
    (void)in_sizes; (void)n_in; (void)out_size; (void)ws_size;
    const float* x    = (const float*)d_in[0];
    const float* W_hx = (const float*)d_in[1];
    const float* b_hx = (const float*)d_in[2];
    const float* W_hh = (const float*)d_in[3];
    const float* b_hh = (const float*)d_in[4];
    const float* W_oh = (const float*)d_in[5];
    const float* b_oh = (const float*)d_in[6];
    float* out = (float*)d_out;

    // ws layout: hX [2][512][512] bf16 = 1 MiB, then 128 flag words
    unsigned short* hX    = (unsigned short*)d_ws;
    unsigned*       flags = (unsigned*)((char*)d_ws + 2u * HID * HID * sizeof(unsigned short));

    ws_init<<<dim3(1), dim3(128), 0, stream>>>(flags);
    rnn_kernel<<<dim3(NRG * NCG), dim3(256), 0, stream>>>(
        x, W_hx, b_hx, W_hh, b_hh, W_oh, b_oh, out, hX, flags);
}

// Round 4
// 4770.452 us; speedup vs baseline: 1.5821x; 1.5821x over previous
//
#include <hip/hip_runtime.h>

#define SEQ   1024
#define HID   512
#define OUTD  10
#define RPB   16              // batch rows per row-group
#define NRG   32              // row-groups
#define NCG   4               // column-group blocks per row-group
#define CPB   (HID/NCG)       // 128 cols per block
#define NT    2               // 16-col MFMA tiles per wave (4 waves x 32 cols)
#define NKT   16              // k-tiles of 32 over HID
#define OKT   (NKT/NCG)       // 4 own k-tiles
#define PCP   (CPB/2)         // 64 colpairs per panel row
#define PANEL (RPB*PCP)       // 1024 u64 words per panel

typedef float f32x4  __attribute__((ext_vector_type(4)));
typedef short bf16x8 __attribute__((ext_vector_type(8)));
typedef int   i32x4  __attribute__((ext_vector_type(4)));
typedef unsigned long long u64;

__device__ __forceinline__ unsigned short f2bf(float f) {
    unsigned u = __builtin_bit_cast(unsigned, f);
    u += 0x7fffu + ((u >> 16) & 1u);           // RTN
    return (unsigned short)(u >> 16);
}
__device__ __forceinline__ float bf2f(unsigned short s) {
    return __builtin_bit_cast(float, ((unsigned)s) << 16);
}

// Exchange buffer hX: u64[2][NCG][NRG][RPB][PCP]. Each word = payload(2 bf16
// cols, low 32b) | step-tag << 32. Written/read with RELAXED agent atomics:
// no L2 writeback/invalidate (that was round 3's 7.3us/step), single-word
// atomicity makes the tag self-validating -> no flags, no fences.
__device__ __forceinline__ size_t panel_base(int buf, int cg, int rg) {
    return (((size_t)buf * NCG + cg) * NRG + rg) * PANEL;
}

__global__ __launch_bounds__(256, 1) void rnn_kernel(
    const float* __restrict__ x,     // [512][1024]
    const float* __restrict__ W_hx,  // [512][1]
    const float* __restrict__ b_hx,  // [512]
    const float* __restrict__ W_hh,  // [512][512]
    const float* __restrict__ b_hh,  // [512]
    const float* __restrict__ W_oh,  // [10][512]
    const float* __restrict__ b_oh,  // [10]
    float* __restrict__ out,         // [512][10]
    u64* __restrict__ hX)            // 2 MiB exchange buffer (ws)
{
    __shared__ unsigned short hL[RPB * HID];   // 16 KB, XOR-swizzled h_t
    __shared__ float obuf[RPB][OUTD];
    char* const hLb = (char*)hL;

    const int tid  = threadIdx.x;
    const int lane = tid & 63;
    const int wv   = tid >> 6;        // 0..3
    const int bid  = blockIdx.x;
    const int rg   = bid & (NRG - 1);
    const int cg   = bid >> 5;
    const int row0 = rg * RPB;
    const int crow = lane & 15;       // A-row / B-col / D-col
    const int kb   = lane >> 4;
    const int dr0  = kb * 4;

    // k-tile permutation: slots 0..3 = own k-tiles (static reg index for the
    // overlap GEMM), slots 4..15 = remote k-tiles in order. kt runtime is only
    // ever used for ADDRESSES; register arrays are indexed by the static slot.
    int ktmap[NKT];
#pragma unroll
    for (int j = 0; j < OKT; ++j) ktmap[j] = cg * OKT + j;
#pragma unroll
    for (int j = 0; j < 12; ++j) {
        int q = j;
        ktmap[OKT + j] = q < cg * OKT ? q : q + OKT;
    }

    // ---- W-slice -> registers (fp32 -> bf16, one-time) ----
    bf16x8 wfr[NT][NKT];
    float  whx[NT], bc[NT];
#pragma unroll
    for (int nt = 0; nt < NT; ++nt) {
        const int col = cg * CPB + wv * 32 + nt * 16 + crow;
        whx[nt] = W_hx[col];
        bc[nt]  = b_hx[col] + b_hh[col];
#pragma unroll
        for (int j = 0; j < NKT; ++j) {
            const float* p = W_hh + (size_t)col * HID + ktmap[j] * 32 + kb * 8;
            bf16x8 v;
#pragma unroll
            for (int e = 0; e < 8; ++e) v[e] = (short)f2bf(p[e]);
            wfr[nt][j] = v;
        }
    }

    int scg[3];
#pragma unroll
    for (int p = 0; p < 3; ++p) scg[p] = p + (p >= cg ? 1 : 0);

    const int amask = (crow & 7) << 4;
    const int frow  = tid >> 4;           // fill row 0..15
    const int fbyte = (tid & 15) * 16;    // fill byte base within 256B stripe

    // poll+fill: wait for the 3 sibling panels' words (tag==want) and write
    // payloads into hL remote regions. Each thread owns 4 consecutive words
    // per panel -> one ds_write_b128 per panel.
    auto poll_fill = [&](int buf, unsigned want) {
        const u64* rp[3];
#pragma unroll
        for (int p = 0; p < 3; ++p)
            rp[p] = hX + panel_base(buf, scg[p], rg) + tid * 4;
        u64 vals[3][4];
        unsigned need = 0xFFFu;
        while (need) {
#pragma unroll
            for (int p = 0; p < 3; ++p)
#pragma unroll
                for (int j = 0; j < 4; ++j) {
                    const unsigned b = 1u << (p * 4 + j);
                    if (need & b) {
                        u64 v = __hip_atomic_load(rp[p] + j, __ATOMIC_RELAXED,
                                                  __HIP_MEMORY_SCOPE_AGENT);
                        if ((unsigned)(v >> 32) == want) {
                            vals[p][j] = v;
                            need &= ~b;
                        }
                    }
                }
            if (need) __builtin_amdgcn_s_sleep(1);
        }
#pragma unroll
        for (int p = 0; p < 3; ++p) {
            i32x4 w;
#pragma unroll
            for (int j = 0; j < 4; ++j) w[j] = (int)(unsigned)vals[p][j];
            int ad = (frow * 1024 + scg[p] * 256 + fbyte) ^ ((frow & 7) << 4);
            *(i32x4*)(hLb + ad) = w;
        }
    };

    f32x4 acc[NT];

    for (int t = 0; t < SEQ; ++t) {
        float xv[4];
#pragma unroll
        for (int r = 0; r < 4; ++r)
            xv[r] = x[(size_t)(row0 + dr0 + r) * SEQ + t];

#pragma unroll
        for (int nt = 0; nt < NT; ++nt) acc[nt] = (f32x4){0.f, 0.f, 0.f, 0.f};

        if (t > 0) {
            // ---- own-k GEMM (A produced locally last step) overlaps the wait ----
#pragma unroll
            for (int j = 0; j < OKT; ++j) {
                int ad = (crow * 1024 + ktmap[j] * 64 + kb * 16) ^ amask;
                bf16x8 a = *(const bf16x8*)(hLb + ad);
                acc[0] = __builtin_amdgcn_mfma_f32_16x16x32_bf16(a, wfr[0][j], acc[0], 0, 0, 0);
                acc[1] = __builtin_amdgcn_mfma_f32_16x16x32_bf16(a, wfr[1][j], acc[1], 0, 0, 0);
            }
            // ---- wait for sibling h_t slices, fill hL ----
            poll_fill(t & 1, (unsigned)t);
            __syncthreads();   // B2: hL remote regions complete
            // ---- remote-k GEMM ----
#pragma unroll
            for (int j = OKT; j < NKT; ++j) {
                int ad = (crow * 1024 + ktmap[j] * 64 + kb * 16) ^ amask;
                bf16x8 a = *(const bf16x8*)(hLb + ad);
                acc[0] = __builtin_amdgcn_mfma_f32_16x16x32_bf16(a, wfr[0][j], acc[0], 0, 0, 0);
                acc[1] = __builtin_amdgcn_mfma_f32_16x16x32_bf16(a, wfr[1][j], acc[1], 0, 0, 0);
            }
            __syncthreads();   // B3: all hL reads done before own-region rewrite
        }

        // ---- epilogue: tanh, publish h_{t+1} (tagged words) + own hL region ----
        u64* const wp = hX + panel_base((t + 1) & 1, cg, rg);
        const u64 tag = ((u64)(unsigned)(t + 1)) << 32;
#pragma unroll
        for (int nt = 0; nt < NT; ++nt) {
#pragma unroll
            for (int r = 0; r < 4; ++r) {
                float pre = acc[nt][r] + xv[r] * whx[nt] + bc[nt];
                float e   = __expf(2.0f * pre);      // overflow -> inf -> h = 1
                float h   = 1.0f - 2.0f / (e + 1.0f);
                unsigned hu = f2bf(h);
                unsigned pv = __shfl_xor(hu, 1);     // partner col (all lanes)
                if (!(crow & 1)) {
                    unsigned payload = hu | (pv << 16);
                    const int row = dr0 + r;
                    const int cpl = wv * 16 + nt * 8 + (crow >> 1);
                    __hip_atomic_store(wp + row * PCP + cpl, payload | tag,
                                       __ATOMIC_RELAXED, __HIP_MEMORY_SCOPE_AGENT);
                    int ad = (row * 1024 + (cg * 64 + cpl) * 4) ^ ((row & 7) << 4);
                    *(unsigned*)(hLb + ad) = payload;
                }
            }
        }
        __syncthreads();   // Be: own hL region visible for next own-k GEMM
    }

    // ---- output projection + softmax (cg==0 blocks only) ----
    if (cg != 0) return;
    poll_fill(SEQ & 1, (unsigned)SEQ);   // gather final remote slices
    __syncthreads();

    if (tid < RPB * OUTD) {
        const int bl = tid / OUTD, j = tid % OUTD;
        const float* wrow = W_oh + (size_t)j * HID;
        float s = b_oh[j];
        for (int k = 0; k < HID; ++k) {
            int ad = (bl * 1024 + k * 2) ^ ((bl & 7) << 4);
            s += bf2f(*(const unsigned short*)(hLb + ad)) * wrow[k];
        }
        obuf[bl][j] = s;
    }
    __syncthreads();
    if (tid < RPB) {
        float m = -1e30f;
#pragma unroll
        for (int j = 0; j < OUTD; ++j) m = fmaxf(m, obuf[tid][j]);
        float e[OUTD], ss = 0.f;
#pragma unroll
        for (int j = 0; j < OUTD; ++j) { e[j] = __expf(obuf[tid][j] - m); ss += e[j]; }
        float inv = 1.0f / ss;
#pragma unroll
        for (int j = 0; j < OUTD; ++j)
            out[(size_t)(row0 + tid) * OUTD + j] = e[j] * inv;
    }
}

extern "C" void kernel_launch(void* const* d_in, const int* in_sizes, int n_in,
                              void* d_out, int out_size, void* d_ws, size_t ws_size,
                              hipStream_t stream) {
    (void)in_sizes; (void)n_in; (void)out_size; (void)ws_size;
    const float* x    = (const float*)d_in[0];
    const float* W_hx = (const float*)d_in[1];
    const float* b_hx = (const float*)d_in[2];
    const float* W_hh = (const float*)d_in[3];
    const float* b_hh = (const float*)d_in[4];
    const float* W_oh = (const float*)d_in[5];
    const float* b_oh = (const float*)d_in[6];
    float* out = (float*)d_out;
    u64* hX = (u64*)d_ws;    // 2 MiB tagged exchange buffer; poison tag
                             // 0xAAAAAAAA never matches a real step tag.

    rnn_kernel<<<dim3(NRG * NCG), dim3(256), 0, stream>>>(
        x, W_hx, b_hx, W_hh, b_hh, W_oh, b_oh, out, hX);
}

// Round 5
// 3071.585 us; speedup vs baseline: 2.4571x; 1.5531x over previous
//
#include <hip/hip_runtime.h>

#define SEQ   1024
#define HID   512
#define OUTD  10
#define RPB   16              // batch rows per row-group
#define NRG   32              // row-groups
#define NCG   2               // column-group blocks per row-group
#define CPB   (HID/NCG)       // 256 cols per block
#define NWV   8               // waves per block (512 threads)
#define CPWV  (CPB/NWV)       // 32 cols per wave
#define NT    (CPWV/16)       // 2 MFMA col-tiles per wave
#define NKT   (HID/32)        // 16 k-tiles of 32
#define OKT   (NKT/NCG)       // 8 own k-tiles
#define PCP   (CPB/2)         // 128 colpairs per panel row
#define PANEL (RPB*PCP)       // 2048 u64 words per panel

typedef float f32x4  __attribute__((ext_vector_type(4)));
typedef short bf16x8 __attribute__((ext_vector_type(8)));
typedef int   i32x4  __attribute__((ext_vector_type(4)));
typedef unsigned long long u64;

__device__ __forceinline__ unsigned short f2bf(float f) {
    unsigned u = __builtin_bit_cast(unsigned, f);
    u += 0x7fffu + ((u >> 16) & 1u);           // RTN
    return (unsigned short)(u >> 16);
}
__device__ __forceinline__ float bf2f(unsigned short s) {
    return __builtin_bit_cast(float, ((unsigned)s) << 16);
}

// hX: u64[2][NCG][NRG][PANEL]; word = 2 bf16 payload | step-tag<<32.
// Relaxed agent atomics only (no fences — round 3 showed acquire/release at
// agent scope costs a full L2 writeback/invalidate per step). Tag makes each
// word self-validating; 0xAAAAAAAA ws-poison never matches a real tag.
__device__ __forceinline__ size_t panel_base(int buf, int cg, int rg) {
    return (((size_t)buf * NCG + cg) * NRG + rg) * PANEL;
}

__global__ __launch_bounds__(512, 2) void rnn_kernel(
    const float* __restrict__ x,     // [512][1024]
    const float* __restrict__ W_hx,  // [512][1]
    const float* __restrict__ b_hx,  // [512]
    const float* __restrict__ W_hh,  // [512][512]
    const float* __restrict__ b_hh,  // [512]
    const float* __restrict__ W_oh,  // [10][512]
    const float* __restrict__ b_oh,  // [10]
    float* __restrict__ out,         // [512][10]
    u64* __restrict__ hX)            // 2 MiB exchange buffer (ws)
{
    __shared__ unsigned short hL[RPB * HID];   // 16 KB, XOR-swizzled h_t
    __shared__ float obuf[RPB][OUTD];
    char* const hLb = (char*)hL;

    const int tid  = threadIdx.x;
    const int lane = tid & 63;
    const int wv   = tid >> 6;        // 0..7
    const int bid  = blockIdx.x;
    const int rg   = bid & (NRG - 1);
    const int cg   = bid >> 5;        // 0..1
    const int row0 = rg * RPB;
    const int crow = lane & 15;       // A-row / B-col / D-col
    const int kb   = lane >> 4;
    const int dr0  = kb * 4;
    const int amask = (crow & 7) << 4;

    // slot->k-tile map: slots 0..7 own (A locally produced), 8..15 remote.
    int ktmap[NKT];
#pragma unroll
    for (int j = 0; j < OKT; ++j) {
        ktmap[j]       = cg * OKT + j;
        ktmap[OKT + j] = (cg ^ 1) * OKT + j;
    }

    // ---- W-slice -> registers (fp32 -> bf16, one-time; 128 VGPR) ----
    bf16x8 wfr[NT][NKT];
    float  whx[NT], bc[NT];
#pragma unroll
    for (int nt = 0; nt < NT; ++nt) {
        const int col = cg * CPB + wv * CPWV + nt * 16 + crow;
        whx[nt] = W_hx[col];
        bc[nt]  = b_hx[col] + b_hh[col];
#pragma unroll
        for (int j = 0; j < NKT; ++j) {
            const float* p = W_hh + (size_t)col * HID + ktmap[j] * 32 + kb * 8;
            bf16x8 v;
#pragma unroll
            for (int e = 0; e < 8; ++e) v[e] = (short)f2bf(p[e]);
            wfr[nt][j] = v;
        }
    }

    // poll+fill: gated — spin on word 0 only (1 load/thread/round), then
    // batch-validate words 1..3 (stores drain ~in order). Fills the sibling
    // 256-col region of hL. Each thread owns 4 consecutive u64 -> one i32x4.
    const int prow  = tid >> 5;            // 0..15
    const int pcp0  = (tid & 31) * 4;      // colpair base
    auto poll_fill = [&](int buf, unsigned want) {
        const u64* rp = hX + panel_base(buf, cg ^ 1, rg) + tid * 4;
        u64 vals[4];
        for (;;) {
            u64 v = __hip_atomic_load(rp, __ATOMIC_RELAXED,
                                      __HIP_MEMORY_SCOPE_AGENT);
            if ((unsigned)(v >> 32) == want) { vals[0] = v; break; }
            __builtin_amdgcn_s_sleep(1);
        }
        unsigned need = 0xEu;
        while (need) {
#pragma unroll
            for (int j = 1; j < 4; ++j) {
                const unsigned b = 1u << j;
                if (need & b) {
                    u64 v = __hip_atomic_load(rp + j, __ATOMIC_RELAXED,
                                              __HIP_MEMORY_SCOPE_AGENT);
                    if ((unsigned)(v >> 32) == want) { vals[j] = v; need &= ~b; }
                }
            }
            if (need) __builtin_amdgcn_s_sleep(1);
        }
        i32x4 w;
#pragma unroll
        for (int j = 0; j < 4; ++j) w[j] = (int)(unsigned)vals[j];
        int ad = (prow * 1024 + (cg ^ 1) * 512 + pcp0 * 4) ^ ((prow & 7) << 4);
        *(i32x4*)(hLb + ad) = w;
    };

    f32x4 acc[NT];

    for (int t = 0; t < SEQ; ++t) {
        float xv[4];
#pragma unroll
        for (int r = 0; r < 4; ++r)
            xv[r] = x[(size_t)(row0 + dr0 + r) * SEQ + t];

#pragma unroll
        for (int nt = 0; nt < NT; ++nt) acc[nt] = (f32x4){0.f, 0.f, 0.f, 0.f};

        if (t > 0) {
            // own-k GEMM (A = our own h-slice, written to hL last step)
#pragma unroll
            for (int j = 0; j < OKT; ++j) {
                int ad = (crow * 1024 + ktmap[j] * 64 + kb * 16) ^ amask;
                bf16x8 a = *(const bf16x8*)(hLb + ad);
                acc[0] = __builtin_amdgcn_mfma_f32_16x16x32_bf16(a, wfr[0][j], acc[0], 0, 0, 0);
                acc[1] = __builtin_amdgcn_mfma_f32_16x16x32_bf16(a, wfr[1][j], acc[1], 0, 0, 0);
            }
            // wait for the sibling slice, fill hL remote region
            poll_fill(t & 1, (unsigned)t);
            __syncthreads();   // B2: remote region complete; own-k reads done
            // remote-k GEMM
#pragma unroll
            for (int j = OKT; j < NKT; ++j) {
                int ad = (crow * 1024 + ktmap[j] * 64 + kb * 16) ^ amask;
                bf16x8 a = *(const bf16x8*)(hLb + ad);
                acc[0] = __builtin_amdgcn_mfma_f32_16x16x32_bf16(a, wfr[0][j], acc[0], 0, 0, 0);
                acc[1] = __builtin_amdgcn_mfma_f32_16x16x32_bf16(a, wfr[1][j], acc[1], 0, 0, 0);
            }
        }

        // ---- epilogue: tanh, publish tagged words first (drain early), then hL ----
        u64* const wp = hX + panel_base((t + 1) & 1, cg, rg);
        const u64 tag = ((u64)(unsigned)(t + 1)) << 32;
#pragma unroll
        for (int nt = 0; nt < NT; ++nt) {
#pragma unroll
            for (int r = 0; r < 4; ++r) {
                float pre = acc[nt][r] + xv[r] * whx[nt] + bc[nt];
                float e   = __expf(2.0f * pre);      // overflow -> inf -> h=1
                float h   = 1.0f - 2.0f / (e + 1.0f);
                unsigned hu = f2bf(h);
                unsigned pv = __shfl_xor(hu, 1);     // partner col (all lanes)
                if (!(crow & 1)) {
                    unsigned payload = hu | (pv << 16);
                    const int row = dr0 + r;
                    const int cpl = wv * 16 + nt * 8 + (crow >> 1);
                    __hip_atomic_store(wp + row * PCP + cpl, payload | tag,
                                       __ATOMIC_RELAXED, __HIP_MEMORY_SCOPE_AGENT);
                    int ad = (row * 1024 + (cg * CPB + wv * CPWV + nt * 16 + crow) * 2)
                             ^ ((row & 7) << 4);
                    *(unsigned*)(hLb + ad) = payload;
                }
            }
        }
        __syncthreads();   // Be: hL own region visible; remote reads retired
    }

    // ---- output projection + softmax (cg==0 blocks only) ----
    if (cg != 0) return;
    poll_fill(SEQ & 1, (unsigned)SEQ);   // final sibling slice
    __syncthreads();

    if (tid < RPB * OUTD) {
        const int bl = tid / OUTD, j = tid % OUTD;
        const float* wrow = W_oh + (size_t)j * HID;
        float s = b_oh[j];
        for (int k = 0; k < HID; ++k) {
            int ad = (bl * 1024 + k * 2) ^ ((bl & 7) << 4);
            s += bf2f(*(const unsigned short*)(hLb + ad)) * wrow[k];
        }
        obuf[bl][j] = s;
    }
    __syncthreads();
    if (tid < RPB) {
        float m = -1e30f;
#pragma unroll
        for (int j = 0; j < OUTD; ++j) m = fmaxf(m, obuf[tid][j]);
        float e[OUTD], ss = 0.f;
#pragma unroll
        for (int j = 0; j < OUTD; ++j) { e[j] = __expf(obuf[tid][j] - m); ss += e[j]; }
        float inv = 1.0f / ss;
#pragma unroll
        for (int j = 0; j < OUTD; ++j)
            out[(size_t)(row0 + tid) * OUTD + j] = e[j] * inv;
    }
}

extern "C" void kernel_launch(void* const* d_in, const int* in_sizes, int n_in,
                              void* d_out, int out_size, void* d_ws, size_t ws_size,
                              hipStream_t stream) {
    (void)in_sizes; (void)n_in; (void)out_size; (void)ws_size;
    const float* x    = (const float*)d_in[0];
    const float* W_hx = (const float*)d_in[1];
    const float* b_hx = (const float*)d_in[2];
    const float* W_hh = (const float*)d_in[3];
    const float* b_hh = (const float*)d_in[4];
    const float* W_oh = (const float*)d_in[5];
    const float* b_oh = (const float*)d_in[6];
    float* out = (float*)d_out;
    u64* hX = (u64*)d_ws;    // 2 MiB tagged exchange; 0xAA poison tag is inert

    rnn_kernel<<<dim3(NRG * NCG), dim3(512), 0, stream>>>(
        x, W_hx, b_hx, W_hh, b_hh, W_oh, b_oh, out, hX);
}